// Round 6
// baseline (205.988 us; speedup 1.0000x reference)
//
#include <hip/hip_runtime.h>
#include <cstdint>
#include <cstddef>

// ManualChebConv: out[b,n,fo] = sum_k Zk[b] @ W[k] + bias
//   Z0 = x, Z1 = L@x, Zk = 2*L@Z_{k-1} - Z_{k-2}, K=5
// B=1024, N=512, F_in=16, F_out=8. L symmetric 512x512 fp32.
//
// R6: R3/R5 spilled because accumulator state (64 AGPR) + 128-reg/wave cap at
// 16 waves/CU left only 64 VGPRs. Fixes:
//  - packed epilogue accumulator: 2 batches per 16-col tile (col=bp*8+fo,
//    MFMA K = bp*16+fi) -> accOut 16 AGPR instead of 32. Total 48 AGPR ->
//    80 VGPRs available.
//  - mi=4 / ct=2 per wave (was 2/4): halves LDS B-read traffic per app
//    (each B-frag feeds 4 M-tiles).
//  - #pragma unroll 2 on ks loop: caps scheduler live-range window (~64 live)
//    so it can't spill-hoist; 16 waves provide TLP latency hiding.
// 1 block/CU (LDS 135 KB), 1024 thr = 16 waves, BT=4.

typedef __attribute__((ext_vector_type(8))) short    frag_ab;  // 8 bf16
typedef __attribute__((ext_vector_type(4))) float    frag_cd;  // 4 fp32
typedef __attribute__((ext_vector_type(8))) uint16_t u16x8;

constexpr int BN    = 512;        // N
constexpr int FIN   = 16;
constexpr int FOUT  = 8;
constexpr int BT    = 4;          // batches per block
constexpr int NCOLS = BT * FIN;   // 64 combined cols
constexpr int LDST  = BN + 16;    // 528: stride = 264 dw = 8 mod 32
constexpr int ZBUF  = NCOLS * LDST;  // 33792 elements per buffer
constexpr int ZOFF  = 16;         // z1 offset: 8-bank shift

__device__ __forceinline__ uint16_t f2bf(float f) {
    uint32_t u = __builtin_bit_cast(uint32_t, f);
    u += 0x7FFFu + ((u >> 16) & 1u);          // round-to-nearest-even
    return (uint16_t)(u >> 16);
}
__device__ __forceinline__ float bf2f(uint16_t h) {
    uint32_t u = ((uint32_t)h) << 16;
    return __builtin_bit_cast(float, u);
}

__global__ void cvtL(const float* __restrict__ Lf, uint16_t* __restrict__ Lb) {
    int i = blockIdx.x * 256 + threadIdx.x;   // 128 blocks x 256 thr x 8 elems
    const float4* p = reinterpret_cast<const float4*>(Lf) + i * 2;
    float4 u0 = p[0], u1 = p[1];
    u16x8 o;
    o[0] = f2bf(u0.x); o[1] = f2bf(u0.y);
    o[2] = f2bf(u0.z); o[3] = f2bf(u0.w);
    o[4] = f2bf(u1.x); o[5] = f2bf(u1.y);
    o[6] = f2bf(u1.z); o[7] = f2bf(u1.w);
    *(reinterpret_cast<u16x8*>(Lb) + i) = o;
}

__global__ __launch_bounds__(1024, 1)
void cheb_kernel(const float* __restrict__ x, const uint16_t* __restrict__ Lb,
                 const float* __restrict__ W, const float* __restrict__ bvec,
                 float* __restrict__ out) {
    __shared__ uint16_t lds[2 * ZBUF + ZOFF];   // 135,200 B
    uint16_t* z0 = lds;
    uint16_t* z1 = lds + ZBUF + ZOFF;

    const int tid  = threadIdx.x;
    const int wave = tid >> 6;                // 0..15
    const int lane = tid & 63;
    const int lr   = lane & 15;               // tile row/col within fragment
    const int q    = lane >> 4;               // quad
    const int who  = wave & 7;                // M-tile group: mt = who + 8i
    const int cg   = wave >> 3;               // col group: cols [cg*32, cg*32+32)

    // ---------------- stage x -> Z0^T (bf16) in z0 ----------------
    const float4* x4 = reinterpret_cast<const float4*>(x + (size_t)blockIdx.x * (BT * BN * FIN));
    {
        int a   = tid;                        // 1024 assignments, one each
        int f0g = a & 3;
        int n8  = (a >> 2) & 63;
        int bl  = a >> 8;
        int jb  = bl * 2048 + n8 * 32 + f0g;
        float4 v[8];
#pragma unroll
        for (int r = 0; r < 8; ++r) v[r] = x4[jb + r * 4];
        int cb = bl * 16 + f0g * 4;
        int nb = n8 * 8;
#pragma unroll
        for (int w = 0; w < 4; ++w) {
            frag_ab pk;
#pragma unroll
            for (int r = 0; r < 8; ++r)
                pk[r] = (short)f2bf(reinterpret_cast<const float*>(&v[r])[w]);
            *reinterpret_cast<frag_ab*>(&z0[(cb + w) * LDST + nb]) = pk;
        }
    }

    const float bv = bvec[lane & 7];          // fo = lr&7; all lanes valid

    frag_cd accOut[4] = {};                   // [mi] packed out tiles: 16 AGPR

    // A bases: L[mt*16+lr][q*8 + ...], mt = who + 8i
    const uint16_t* aRow = Lb + (who * 16 + lr) * BN + q * 8;

    // One application: dst = L@cur (first) or 2*L@cur - dst (in-place).
    // acc starts at -0.5*Z_{k-2} (prologue), writeback stores 2*acc.
    auto app = [&](const uint16_t* cur, uint16_t* dst, bool first) {
        frag_cd acc[4][2];                    // [mi][c]: 32 AGPR
#pragma unroll
        for (int i = 0; i < 4; ++i) {
            int row0 = (who + 8 * i) * 16 + q * 4;
#pragma unroll
            for (int c = 0; c < 2; ++c) {
                if (first) {
                    acc[i][c] = frag_cd{0.f, 0.f, 0.f, 0.f};
                } else {
                    const uint16_t* dp = dst + ((cg * 2 + c) * 16 + lr) * LDST + row0;
                    ushort4 pv = *reinterpret_cast<const ushort4*>(dp);
                    acc[i][c][0] = -0.5f * bf2f(pv.x);
                    acc[i][c][1] = -0.5f * bf2f(pv.y);
                    acc[i][c][2] = -0.5f * bf2f(pv.z);
                    acc[i][c][3] = -0.5f * bf2f(pv.w);
                }
            }
        }

        const uint16_t* bBase = cur + (cg * 32 + lr) * LDST + q * 8;
#pragma unroll 2
        for (int ks = 0; ks < 16; ++ks) {
            frag_ab b0 = *reinterpret_cast<const frag_ab*>(bBase + ks * 32);
            frag_ab b1 = *reinterpret_cast<const frag_ab*>(bBase + 16 * LDST + ks * 32);
            frag_ab a0 = *reinterpret_cast<const frag_ab*>(aRow + 0 * 128 * BN + ks * 32);
            frag_ab a1 = *reinterpret_cast<const frag_ab*>(aRow + 1 * 128 * BN + ks * 32);
            frag_ab a2 = *reinterpret_cast<const frag_ab*>(aRow + 2 * 128 * BN + ks * 32);
            frag_ab a3 = *reinterpret_cast<const frag_ab*>(aRow + 3 * 128 * BN + ks * 32);
            acc[0][0] = __builtin_amdgcn_mfma_f32_16x16x32_bf16(a0, b0, acc[0][0], 0, 0, 0);
            acc[0][1] = __builtin_amdgcn_mfma_f32_16x16x32_bf16(a0, b1, acc[0][1], 0, 0, 0);
            acc[1][0] = __builtin_amdgcn_mfma_f32_16x16x32_bf16(a1, b0, acc[1][0], 0, 0, 0);
            acc[1][1] = __builtin_amdgcn_mfma_f32_16x16x32_bf16(a1, b1, acc[1][1], 0, 0, 0);
            acc[2][0] = __builtin_amdgcn_mfma_f32_16x16x32_bf16(a2, b0, acc[2][0], 0, 0, 0);
            acc[2][1] = __builtin_amdgcn_mfma_f32_16x16x32_bf16(a2, b1, acc[2][1], 0, 0, 0);
            acc[3][0] = __builtin_amdgcn_mfma_f32_16x16x32_bf16(a3, b0, acc[3][0], 0, 0, 0);
            acc[3][1] = __builtin_amdgcn_mfma_f32_16x16x32_bf16(a3, b1, acc[3][1], 0, 0, 0);
        }

        const float s = first ? 1.0f : 2.0f;
#pragma unroll
        for (int i = 0; i < 4; ++i) {
            int row0 = (who + 8 * i) * 16 + q * 4;
#pragma unroll
            for (int c = 0; c < 2; ++c) {
                uint16_t* dp = dst + ((cg * 2 + c) * 16 + lr) * LDST + row0;
                ushort4 nv;
                nv.x = f2bf(s * acc[i][c][0]);
                nv.y = f2bf(s * acc[i][c][1]);
                nv.z = f2bf(s * acc[i][c][2]);
                nv.w = f2bf(s * acc[i][c][3]);
                *reinterpret_cast<ushort4*>(dp) = nv;
            }
        }
    };

    // Packed epilogue for cheb index kc (src holds Zkc):
    //   D[n][col=bp*8+fo] += sum_{k=bp*16+fi} A[n][k] * B[k][col]
    //   A[n][(bp,fi)] = Zkc[batch=cg*2+bp, n, fi];  B = block-diag(W[kc])
    auto epi1 = [&](const uint16_t* src, int kc) {
        frag_ab wfr;
        const int fo = lr & 7, bpc = lr >> 3, bpk = q >> 1;
#pragma unroll
        for (int jj = 0; jj < 8; ++jj) {
            int fi = (q & 1) * 8 + jj;
            float val = (bpk == bpc) ? W[kc * (FIN * FOUT) + fi * FOUT + fo] : 0.0f;
            wfr[jj] = (short)f2bf(val);
        }
        const int cc = (cg * 2 + bpk) * 16 + (q & 1) * 8;
        const uint16_t* sp = src + cc * LDST;
#pragma unroll
        for (int i = 0; i < 4; ++i) {
            int n = (who + 8 * i) * 16 + lr;
            frag_ab afr;
#pragma unroll
            for (int jj = 0; jj < 8; ++jj) afr[jj] = (short)sp[jj * LDST + n];
            accOut[i] = __builtin_amdgcn_mfma_f32_16x16x32_bf16(
                afr, wfr, accOut[i], 0, 0, 0);
        }
    };

    __syncthreads();
    app(z0, z1, true);        // Z1 -> z1
    __syncthreads();
    epi1(z0, 0); epi1(z1, 1); // out += Z0@W0 + Z1@W1
    __syncthreads();
    app(z1, z0, false);       // Z2 -> z0 (over Z0)
    __syncthreads();
    app(z0, z1, false);       // Z3 -> z1 (over Z1)
    __syncthreads();
    epi1(z0, 2); epi1(z1, 3); // out += Z2@W2 + Z3@W3
    __syncthreads();
    app(z1, z0, false);       // Z4 -> z0 (over Z2)
    __syncthreads();
    epi1(z0, 4);              // out += Z4@W4

    // ---------------- store (all 64 lanes valid) ----------------
    {
        const int fo    = lane & 7;
        const int batch = cg * 2 + (lr >> 3);
        float* ob = out + (size_t)blockIdx.x * (BT * BN * FOUT) + batch * (BN * FOUT) + fo;
#pragma unroll
        for (int i = 0; i < 4; ++i) {
            int row0 = (who + 8 * i) * 16 + q * 4;
            float* op = ob + row0 * FOUT;
            op[0 * FOUT] = accOut[i][0] + bv;
            op[1 * FOUT] = accOut[i][1] + bv;
            op[2 * FOUT] = accOut[i][2] + bv;
            op[3 * FOUT] = accOut[i][3] + bv;
        }
    }
}

extern "C" void kernel_launch(void* const* d_in, const int* in_sizes, int n_in,
                              void* d_out, int out_size, void* d_ws, size_t ws_size,
                              hipStream_t stream) {
    const float* x  = (const float*)d_in[0];   // [1024,512,16]
    const float* Lf = (const float*)d_in[1];   // [512,512]
    const float* W  = (const float*)d_in[2];   // [5,16,8]
    const float* bv = (const float*)d_in[3];   // [8]
    float* out = (float*)d_out;                // [1024,512,8]

    uint16_t* Lb = (uint16_t*)d_ws;            // 512 KB bf16 copy of L
    cvtL<<<dim3(128), dim3(256), 0, stream>>>(Lf, Lb);
    cheb_kernel<<<dim3(256), dim3(1024), 0, stream>>>(x, Lb, W, bv, out);
}